// Round 9
// baseline (184.394 us; speedup 1.0000x reference)
//
#include <hip/hip_runtime.h>
#include <hip/hip_bf16.h>

#define NB 4
#define NT 1024
#define ND 512
#define NH 8
#define NKC 64

typedef __bf16 bf16x8 __attribute__((ext_vector_type(8)));
typedef float f32x4 __attribute__((ext_vector_type(4)));
typedef unsigned int u32;

__device__ __forceinline__ f32x4 MFMA(bf16x8 a, bf16x8 b, f32x4 c) {
    return __builtin_amdgcn_mfma_f32_16x16x32_bf16(a, b, c, 0, 0, 0);
}
__device__ __forceinline__ unsigned short f2bu(float v) {
    __hip_bfloat16 b = __float2bfloat16(v);
    return *(unsigned short*)&b;
}
__device__ __forceinline__ void split1(float v, unsigned short& h, unsigned short& l)
{
    __hip_bfloat16 hb = __float2bfloat16(v);
    float r = v - __bfloat162float(hb);
    __hip_bfloat16 lb = __float2bfloat16(r);
    h = *(unsigned short*)&hb;
    l = *(unsigned short*)&lb;
}
__device__ __forceinline__ void splitpack(const float4 a, const float4 b, uint4& h, uint4& l)
{
    union { unsigned short u[8]; uint4 v; } H, L;
    const float f[8] = {a.x, a.y, a.z, a.w, b.x, b.y, b.z, b.w};
    #pragma unroll
    for (int j = 0; j < 8; ++j) split1(f[j], H.u[j], L.u[j]);
    h = H.v; l = L.v;
}
// async global->LDS, 16B per lane. LDS dest = wave-uniform base + lane*16.
__device__ __forceinline__ void gl16(const unsigned short* g, unsigned short* l) {
    __builtin_amdgcn_global_load_lds(
        (const __attribute__((address_space(1))) u32*)g,
        (__attribute__((address_space(3))) u32*)l, 16, 0, 0);
}

// w[k][n] fp32 -> wT hi/lo bf16 [n][k]
__global__ __launch_bounds__(256)
void splitT_kernel(const float* __restrict__ w0, const float* __restrict__ w1,
                   const float* __restrict__ w2, const float* __restrict__ w3,
                   unsigned short* __restrict__ wT)
{
    __shared__ float tl[32][33];
    const float* w = (blockIdx.z == 0) ? w0 : (blockIdx.z == 1) ? w1
                   : (blockIdx.z == 2) ? w2 : w3;
    unsigned short* hi = wT + (size_t)blockIdx.z * 2 * (ND * ND);
    unsigned short* lo = hi + ND * ND;
    const int t = threadIdx.x;
    const int x0 = blockIdx.x * 32, y0 = blockIdx.y * 32;
    {
        const int r = t >> 3, c = (t & 7) * 4;
        const float4 v = *(const float4*)&w[(size_t)(y0 + r) * ND + x0 + c];
        tl[r][c] = v.x; tl[r][c+1] = v.y; tl[r][c+2] = v.z; tl[r][c+3] = v.w;
    }
    __syncthreads();
    {
        const int nr = t >> 3, k4 = (t & 7) * 4;
        unsigned short hh[4], ll[4];
        #pragma unroll
        for (int j = 0; j < 4; ++j) split1(tl[k4 + j][nr], hh[j], ll[j]);
        ushort4 h = make_ushort4(hh[0], hh[1], hh[2], hh[3]);
        ushort4 l = make_ushort4(ll[0], ll[1], ll[2], ll[3]);
        *(ushort4*)&hi[(size_t)(x0 + nr) * ND + y0 + k4] = h;
        *(ushort4*)&lo[(size_t)(x0 + nr) * ND + y0 + k4] = l;
    }
}

// ===========================================================================
// Projections: 64(m) x 128(n) tile, BK=32. A reg-staged (fp32->hi/lo split
// overlapped with MFMA), B staged via global_load_lds DMA into LINEAR LDS
// with source-XOR swizzle (chunk ^= (row>>1)&3) -> 2-way banks on read.
// q -> hi/lo [bh][t][kc]; k -> bf16 [bh][t][kc]; v -> TILED.
// ===========================================================================
__global__ __launch_bounds__(256, 3)
void proj_mfma(const float* __restrict__ x, const float* __restrict__ cc,
               const unsigned short* __restrict__ wT,
               const float* __restrict__ bq, const float* __restrict__ bk,
               const float* __restrict__ bv,
               unsigned short* __restrict__ qh_o, unsigned short* __restrict__ ql_o,
               unsigned short* __restrict__ kh_o, unsigned short* __restrict__ vh_o)
{
    __shared__ unsigned short smem[13312];           // 26 KB
    unsigned short* Ah = smem;                       // 64*40  = 2560 (padded)
    unsigned short* Al = smem + 2560;                // 64*40
    unsigned short* Bh = smem + 5120;                // 128*32 = 4096 (linear)
    unsigned short* Bl = smem + 9216;                // 128*32
    unsigned short* Tr = smem;                       // alias: 256*40 = 10240

    // XCD-aware remap of grid (4, 64, 3): 768 blocks, chunk 96 per XCD.
    const int hw = blockIdx.x + 4 * blockIdx.y + 256 * blockIdx.z;
    const int swz = (hw & 7) * 96 + (hw >> 3);
    const int xt = swz & 3;
    const int yt = (swz >> 2) & 63;
    const int which = swz >> 8;

    const float* A_g = (which == 0) ? x : cc;
    const unsigned short* Bh_g = wT + (size_t)which * 2 * (ND * ND);
    const unsigned short* Bl_g = Bh_g + ND * ND;
    const float* bias = (which == 0) ? bq : (which == 1) ? bk : bv;

    const int tid = threadIdx.x, l = tid & 63, w = tid >> 6;
    const int quad = l >> 4, lc = l & 15;
    const int wm = w & 1, wn = w >> 1;
    const int n0 = xt * 128, m0 = yt * 64;

    const int am = tid >> 2, ak = (tid & 3) * 8;
    const size_t aG = (size_t)(m0 + am) * ND + ak;

    // B DMA lane mapping: each wave stages rows [w*32, w*32+32), 2 loads of
    // 16 rows per buffer. lane -> (row lr, chunk lc4), src chunk XOR-swizzled.
    const int lr = l >> 2, lc4 = l & 3;
    const int lcs = lc4 ^ ((lr >> 1) & 3);
    const unsigned short* bsrcH0 = Bh_g + (size_t)(n0 + w * 32 + lr) * ND + lcs * 8;
    const unsigned short* bsrcH1 = bsrcH0 + 16 * ND;
    const unsigned short* bsrcL0 = Bl_g + (size_t)(n0 + w * 32 + lr) * ND + lcs * 8;
    const unsigned short* bsrcL1 = bsrcL0 + 16 * ND;
    unsigned short* bdstH0 = Bh + (w * 32) * 32;
    unsigned short* bdstH1 = Bh + (w * 32 + 16) * 32;
    unsigned short* bdstL0 = Bl + (w * 32) * 32;
    unsigned short* bdstL1 = Bl + (w * 32 + 16) * 32;

    float4 ra0 = *(const float4*)&A_g[aG];
    float4 ra1 = *(const float4*)&A_g[aG + 4];
    uint4 h0, l0;
    splitpack(ra0, ra1, h0, l0);

    // read-side swizzle for B fragments: f(row) = (row>>1)&3 = (lc>>1)&3 here
    const int fsw = (lc >> 1) & 3;
    const int bchunk = (quad ^ fsw) * 8;

    f32x4 acc[2][4];
    #pragma unroll
    for (int mi = 0; mi < 2; ++mi)
        #pragma unroll
        for (int ni = 0; ni < 4; ++ni) acc[mi][ni] = (f32x4){0.f, 0.f, 0.f, 0.f};

    for (int k0 = 0; k0 < ND; k0 += 32) {
        __syncthreads();
        {
            *(uint4*)&Ah[am * 40 + ak] = h0;
            *(uint4*)&Al[am * 40 + ak] = l0;
            gl16(bsrcH0 + k0, bdstH0);
            gl16(bsrcH1 + k0, bdstH1);
            gl16(bsrcL0 + k0, bdstL0);
            gl16(bsrcL1 + k0, bdstL1);
        }
        __syncthreads();
        if (k0 + 32 < ND) {
            const size_t aN = aG + k0 + 32;
            ra0 = *(const float4*)&A_g[aN];
            ra1 = *(const float4*)&A_g[aN + 4];
        }

        bf16x8 ah[2], al2[2], bh[4], bl[4];
        #pragma unroll
        for (int mi = 0; mi < 2; ++mi) {
            const int ar = (wm * 32 + mi * 16 + lc) * 40 + quad * 8;
            ah[mi] = *(const bf16x8*)&Ah[ar];
            al2[mi] = *(const bf16x8*)&Al[ar];
        }
        #pragma unroll
        for (int ni = 0; ni < 4; ++ni) {
            const int br = (wn * 64 + ni * 16 + lc) * 32 + bchunk;
            bh[ni] = *(const bf16x8*)&Bh[br];
            bl[ni] = *(const bf16x8*)&Bl[br];
        }
        #pragma unroll
        for (int mi = 0; mi < 2; ++mi)
            #pragma unroll
            for (int ni = 0; ni < 4; ++ni) {
                acc[mi][ni] = MFMA(al2[mi], bh[ni], acc[mi][ni]);
                acc[mi][ni] = MFMA(ah[mi], bl[ni], acc[mi][ni]);
                acc[mi][ni] = MFMA(ah[mi], bh[ni], acc[mi][ni]);
            }
        if (k0 + 32 < ND) splitpack(ra0, ra1, h0, l0);   // overlaps next MFMA wait
    }

    // ---- epilogue ----
    const int bb = m0 >> 10, tt0 = m0 & 1023;
    const int hh = tt0 >> 7, cch0 = (tt0 & 127) >> 1;
    const int bh_idx = bb * NH + hh;

    if (which == 2) {   // v: tiled store [bh][t>>6][cch][t&63]
        #pragma unroll
        for (int ni = 0; ni < 4; ++ni) {
            const int n = n0 + wn * 64 + ni * 16 + lc;
            const float bval = bias[n];
            #pragma unroll
            for (int mi = 0; mi < 2; ++mi)
                #pragma unroll
                for (int r = 0; r < 4; ++r) {
                    const int mloc = wm * 32 + mi * 16 + quad * 4 + r;
                    const int cch = cch0 + (mloc >> 1);
                    const int t = (mloc & 1) * 512 + n;
                    vh_o[(((size_t)bh_idx * 16 + (t >> 6)) * 64 + cch) * 64 + (t & 63)] =
                        f2bu(acc[mi][ni][r] + bval);
                }
        }
        return;
    }

    const int npass = (which == 0) ? 2 : 1;
    unsigned short* outp[2] = {(which == 0) ? qh_o : kh_o, ql_o};

    for (int pass = 0; pass < npass; ++pass) {
        __syncthreads();
        #pragma unroll
        for (int ni = 0; ni < 4; ++ni) {
            const int nloc = wn * 64 + ni * 16 + lc;
            const float bval = bias[n0 + nloc];
            #pragma unroll
            for (int mi = 0; mi < 2; ++mi)
                #pragma unroll
                for (int r = 0; r < 4; ++r) {
                    const int mloc = wm * 32 + mi * 16 + quad * 4 + r;
                    const float val = acc[mi][ni][r] + bval;
                    unsigned short hs, ls;
                    if (which == 0) { split1(val, hs, ls); }
                    else { hs = f2bu(val); ls = 0; }
                    Tr[((mloc & 1) * 128 + nloc) * 40 + (mloc >> 1)] =
                        (pass == 0) ? hs : ls;
                }
        }
        __syncthreads();
        {
            const int t = (tid >> 7) * 512 + n0 + (tid & 127);
            const size_t oa = ((size_t)bh_idx * NT + t) * NKC + cch0;
            const uint4 v0 = *(const uint4*)&Tr[tid * 40];
            const uint4 v1 = *(const uint4*)&Tr[tid * 40 + 8];
            const uint4 v2 = *(const uint4*)&Tr[tid * 40 + 16];
            const uint4 v3 = *(const uint4*)&Tr[tid * 40 + 24];
            *(uint4*)&outp[pass][oa]      = v0;
            *(uint4*)&outp[pass][oa + 8]  = v1;
            *(uint4*)&outp[pass][oa + 16] = v2;
            *(uint4*)&outp[pass][oa + 24] = v3;
        }
    }
}

// ===========================================================================
// Output projection: 64x64 tile. ALL staging (A = att bf16, B = wo hi/lo)
// via global_load_lds DMA, linear LDS + source-XOR swizzle. No reg round-trip.
// ===========================================================================
__global__ __launch_bounds__(256, 4)
void outproj_mfma(const unsigned short* __restrict__ a_g,
                  const unsigned short* __restrict__ wTh,
                  const float* __restrict__ bo, float* __restrict__ out)
{
    __shared__ unsigned short smem2[6144];           // 12 KB
    unsigned short* As = smem2;                      // 64*32 linear
    unsigned short* Bh = smem2 + 2048;
    unsigned short* Bl = smem2 + 4096;
    const unsigned short* Bl_g = wTh + ND * ND;
    const int tid = threadIdx.x, l = tid & 63, w = tid >> 6;
    const int quad = l >> 4, lc = l & 15;
    const int wm = w & 1, wn = w >> 1;

    const int hw = blockIdx.x + 8 * blockIdx.y;      // grid (8, 64): 512 blocks
    const int swz = (hw & 7) * 64 + (hw >> 3);
    const int n0 = (swz & 7) * 64, m0 = (swz >> 3) * 64;

    // DMA lane mapping: each wave stages 16 rows per buffer (64 rows / 4 waves)
    const int lr = l >> 2, lc4 = l & 3;
    const int lcs = lc4 ^ ((lr >> 1) & 3);
    const unsigned short* asrc  = a_g + (size_t)(m0 + w * 16 + lr) * ND + lcs * 8;
    const unsigned short* bhsrc = wTh + (size_t)(n0 + w * 16 + lr) * ND + lcs * 8;
    const unsigned short* blsrc = Bl_g + (size_t)(n0 + w * 16 + lr) * ND + lcs * 8;
    unsigned short* adst = As + (w * 16) * 32;
    unsigned short* bhdst = Bh + (w * 16) * 32;
    unsigned short* bldst = Bl + (w * 16) * 32;

    const int fsw = (lc >> 1) & 3;
    const int chunk = (quad ^ fsw) * 8;

    f32x4 acc[2][2];
    #pragma unroll
    for (int mi = 0; mi < 2; ++mi)
        #pragma unroll
        for (int ni = 0; ni < 2; ++ni) acc[mi][ni] = (f32x4){0.f, 0.f, 0.f, 0.f};

    for (int k0 = 0; k0 < ND; k0 += 32) {
        __syncthreads();
        gl16(asrc + k0, adst);
        gl16(bhsrc + k0, bhdst);
        gl16(blsrc + k0, bldst);
        __syncthreads();

        bf16x8 ab[2], bhf[2], blf[2];
        #pragma unroll
        for (int mi = 0; mi < 2; ++mi)
            ab[mi] = *(const bf16x8*)&As[(wm * 32 + mi * 16 + lc) * 32 + chunk];
        #pragma unroll
        for (int ni = 0; ni < 2; ++ni) {
            const int br = (wn * 32 + ni * 16 + lc) * 32 + chunk;
            bhf[ni] = *(const bf16x8*)&Bh[br];
            blf[ni] = *(const bf16x8*)&Bl[br];
        }
        #pragma unroll
        for (int mi = 0; mi < 2; ++mi)
            #pragma unroll
            for (int ni = 0; ni < 2; ++ni) {
                acc[mi][ni] = MFMA(ab[mi], bhf[ni], acc[mi][ni]);
                acc[mi][ni] = MFMA(ab[mi], blf[ni], acc[mi][ni]);
            }
    }

    #pragma unroll
    for (int ni = 0; ni < 2; ++ni) {
        const int n = n0 + wn * 32 + ni * 16 + lc;
        const float bval = bo[n];
        #pragma unroll
        for (int mi = 0; mi < 2; ++mi)
            #pragma unroll
            for (int r = 0; r < 4; ++r) {
                const int m = m0 + wm * 32 + mi * 16 + quad * 4 + r;
                out[(size_t)m * ND + n] = acc[mi][ni][r] + bval;
            }
    }
}

// ===========================================================================
// MFMA flash attention, s-split ACROSS WAVE HALVES of one 512-thread block.
// Waves 0-3: s in [0,512), waves 4-7: s in [512,1024); same 64-row q-tile.
// K/V are loaded PER-LANE directly into registers (MFMA fragment = contiguous
// 16B in global layout) -> NO K/V LDS, NO barriers in the s-loop. Only P
// (per-wave) and the static emb blocks live in LDS. Band logic gated on diag
// tiles. grid (16, 8, 4), XCD swizzle.
// ===========================================================================
__global__ __launch_bounds__(512, 4)
void attn_mfma(const unsigned short* __restrict__ qh_g, const unsigned short* __restrict__ ql_g,
               const unsigned short* __restrict__ kh_g,
               const unsigned short* __restrict__ vh_g,
               const float* __restrict__ embk, const float* __restrict__ embv,
               unsigned short* __restrict__ ath)
{
    __shared__ unsigned short smem[17408];            // 34 KB
    // [0,13312)      Ps: 8 x 16*104
    // [13312,15872)  Ev emb_v padded 64x40
    // [15872,17408)  bandv 64*12 f32
    unsigned short* Ps  = smem;
    unsigned short* Ev  = smem + 13312;
    float* bandv = (float*)(smem + 15872);
    unsigned short* EkH = smem;                       // alias over Ps (preamble)
    unsigned short* EkL = EkH + 1152;

    const int tid = threadIdx.x, l = tid & 63, w = tid >> 6;
    const int quad = l >> 4, lc = l & 15;
    const int g = w & 3;                              // q-row group
    const int h = w >> 2;                             // s-half

    // XCD-aware remap of grid (16, 8, 4): 512 blocks, chunk 64 per XCD.
    const int hw = blockIdx.x + 16 * blockIdx.y + 128 * blockIdx.z;
    const int swz = (hw & 7) * 64 + (hw >> 3);
    const int q0 = (swz & 15) * 64;
    const int hh = (swz >> 4) & 7, bb = swz >> 7;

    const int sBeg = h * 512;
    const int bh = bb * NH + hh;
    const size_t qkBase = (size_t)bh * NT * NKC;
    const size_t vtBase = (size_t)bh * (16 * 64 * 64);

    for (int idx = tid; idx < 16 * 72; idx += 512) {
        const int d = idx / 72, kc = idx - d * 72;
        const float v = (d < 9 && kc < 64) ? embk[d * 64 + kc] : 0.f;
        unsigned short hs, ls;
        split1(v, hs, ls);
        EkH[idx] = hs;
        EkL[idx] = ls;
    }
    for (int idx = tid; idx < 64 * 40; idx += 512) {
        const int c = idx / 40, d = idx - c * 40;
        Ev[idx] = f2bu((d < 9) ? embv[d * 64 + c] : 0.f);
    }
    __syncthreads();

    bf16x8 qh[2], ql[2];
    {
        const int qg = q0 + g * 16 + lc;
        const size_t qa = qkBase + (size_t)qg * NKC + quad * 8;
        qh[0] = *(const bf16x8*)&qh_g[qa];
        qh[1] = *(const bf16x8*)&qh_g[qa + 32];
        ql[0] = *(const bf16x8*)&ql_g[qa];
        ql[1] = *(const bf16x8*)&ql_g[qa + 32];
    }

    {
        f32x4 accB = (f32x4){0.f, 0.f, 0.f, 0.f};
        #pragma unroll
        for (int kk = 0; kk < 2; ++kk) {
            const bf16x8 ebh = *(const bf16x8*)&EkH[lc * 72 + kk * 32 + quad * 8];
            const bf16x8 ebl = *(const bf16x8*)&EkL[lc * 72 + kk * 32 + quad * 8];
            accB = MFMA(ql[kk], ebh, accB);
            accB = MFMA(qh[kk], ebl, accB);
            accB = MFMA(qh[kk], ebh, accB);
        }
        __syncthreads();              // EkH/EkL dead after this point
        if (h == 0 && lc <= 8) {
            #pragma unroll
            for (int r = 0; r < 4; ++r)
                bandv[(g * 16 + quad * 4 + r) * 12 + lc] = accB[r];
        }
    }
    unsigned short* P = Ps + w * 1664;
    {
        // zero band/pad cols 64..96 for all 16 P rows once
        const int zr = l >> 2, zc = 64 + (l & 3) * 8;
        *(uint4*)&P[zr * 104 + zc] = (uint4){0u, 0u, 0u, 0u};
    }
    __syncthreads();                  // bandv visible to all waves

    // per-lane K/V fragment bases (contiguous 16B per fragment)
    const unsigned short* kF = kh_g + qkBase + (size_t)(sBeg + lc) * NKC + quad * 8;
    const unsigned short* vF = vh_g + vtBase + (size_t)(sBeg >> 6) * 4096 + lc * 64 + quad * 8;

    f32x4 O[4];
    #pragma unroll
    for (int ci = 0; ci < 4; ++ci) O[ci] = (f32x4){0.f, 0.f, 0.f, 0.f};
    float l_run[4] = {0.f, 0.f, 0.f, 0.f};
    bool prevdiag = false;

    for (int s0 = sBeg; s0 < sBeg + 512; s0 += 64) {
        const int st = s0 - sBeg;
        const int sd = s0 - q0;
        const bool diag = (sd >= -64) && (sd <= 64);   // wave-uniform

        // ---- QK^T: per-lane K fragments straight from global/L2 ----
        f32x4 S[4];
        #pragma unroll
        for (int ni = 0; ni < 4; ++ni) {
            const bf16x8 k0 = *(const bf16x8*)&kF[(size_t)(st + ni * 16) * NKC];
            const bf16x8 k1 = *(const bf16x8*)&kF[(size_t)(st + ni * 16) * NKC + 32];
            f32x4 a = (f32x4){0.f, 0.f, 0.f, 0.f};
            a = MFMA(ql[0], k0, a);
            a = MFMA(qh[0], k0, a);
            a = MFMA(ql[1], k1, a);
            a = MFMA(qh[1], k1, a);
            S[ni] = a;
        }

        // ---- V fragments issued here; latency covered by softmax ----
        bf16x8 vf[4][2];
        #pragma unroll
        for (int ci = 0; ci < 4; ++ci)
            #pragma unroll
            for (int ks = 0; ks < 2; ++ks)
                vf[ci][ks] = *(const bf16x8*)&vF[(size_t)(st >> 6) * 4096 + ci * 1024 + ks * 32];

        // ---- band add (diag tiles only) ----
        if (diag) {
            #pragma unroll
            for (int ni = 0; ni < 4; ++ni)
                #pragma unroll
                for (int r = 0; r < 4; ++r) {
                    const int ql64 = g * 16 + quad * 4 + r;
                    const int dp4 = (s0 + ni * 16 + lc) - (q0 + ql64) + 4;
                    if (dp4 >= 0 && dp4 <= 8) S[ni][r] += bandv[ql64 * 12 + dp4];
                }
        }
        // ---- scale + exp (no max subtraction) ----
        #pragma unroll
        for (int ni = 0; ni < 4; ++ni)
            #pragma unroll
            for (int r = 0; r < 4; ++r)
                S[ni][r] = __expf(S[ni][r] * 0.125f);
        #pragma unroll
        for (int r = 0; r < 4; ++r)
            l_run[r] += S[0][r] + S[1][r] + S[2][r] + S[3][r];

        // ---- P -> per-wave LDS (within-wave dependency only) ----
        if (diag || prevdiag) {        // clear band cols only when stale
            const int zr = l >> 2, zc = 64 + (l & 3) * 4;
            *(ushort4*)&P[zr * 104 + zc] = make_ushort4(0, 0, 0, 0);
        }
        if (diag) {
            #pragma unroll
            for (int ni = 0; ni < 4; ++ni)
                #pragma unroll
                for (int r = 0; r < 4; ++r) {
                    const int prow = quad * 4 + r;
                    const unsigned short pb = f2bu(S[ni][r]);
                    P[prow * 104 + ni * 16 + lc] = pb;
                    const int dp4 = (s0 + ni * 16 + lc) - (q0 + g * 16 + prow) + 4;
                    if (dp4 >= 0 && dp4 <= 8) P[prow * 104 + 64 + dp4] = pb;
                }
        } else {
            #pragma unroll
            for (int ni = 0; ni < 4; ++ni)
                #pragma unroll
                for (int r = 0; r < 4; ++r) {
                    const int prow = quad * 4 + r;
                    P[prow * 104 + ni * 16 + lc] = f2bu(S[ni][r]);
                }
        }

        // ---- PV: ks=0,1 from V regs, ks=2 from static emb block ----
        #pragma unroll
        for (int ks = 0; ks < 2; ++ks) {
            const bf16x8 pa = *(const bf16x8*)&P[lc * 104 + ks * 32 + quad * 8];
            #pragma unroll
            for (int ci = 0; ci < 4; ++ci)
                O[ci] = MFMA(pa, vf[ci][ks], O[ci]);
        }
        {
            const bf16x8 pa = *(const bf16x8*)&P[lc * 104 + 64 + quad * 8];
            #pragma unroll
            for (int ci = 0; ci < 4; ++ci) {
                const bf16x8 vb = *(const bf16x8*)&Ev[(ci * 16 + lc) * 40 + quad * 8];
                O[ci] = MFMA(pa, vb, O[ci]);
            }
        }
        prevdiag = diag;
    }

    // ---- epilogue: reduce l over the 16 col-lanes, merge halves in LDS ----
    #pragma unroll
    for (int r = 0; r < 4; ++r) {
        float v = l_run[r];
        v += __shfl_xor(v, 1); v += __shfl_xor(v, 2);
        v += __shfl_xor(v, 4); v += __shfl_xor(v, 8);
        l_run[r] = v;
    }

    __syncthreads();                         // all waves done with P tiles
    float* Oex = (float*)smem;               // 64q x 64c f32 = 16 KB (over Ps)
    float* l1s = bandv;                      // 64 f32 (bandv dead after loop)
    const int qloc0 = g * 16 + quad * 4;

    if (h == 1) {
        #pragma unroll
        for (int ci = 0; ci < 4; ++ci)
            #pragma unroll
            for (int r = 0; r < 4; ++r)
                Oex[(qloc0 + r) * 64 + ci * 16 + lc] = O[ci][r];
        if (lc == 0) {
            #pragma unroll
            for (int r = 0; r < 4; ++r)
                l1s[qloc0 + r] = l_run[r];
        }
    }
    __syncthreads();
    if (h == 0) {
        float linv[4];
        #pragma unroll
        for (int r = 0; r < 4; ++r)
            linv[r] = 1.f / (l_run[r] + l1s[qloc0 + r]);
        #pragma unroll
        for (int ci = 0; ci < 4; ++ci) {
            const int c = ci * 16 + lc;
            const int row = hh * 128 + 2 * c + (q0 >> 9);
            unsigned short o[4];
            #pragma unroll
            for (int r = 0; r < 4; ++r)
                o[r] = f2bu((O[ci][r] + Oex[(qloc0 + r) * 64 + c]) * linv[r]);
            *(ushort4*)&ath[((size_t)bb * NT + row) * ND + (q0 & 511) + qloc0] =
                make_ushort4(o[0], o[1], o[2], o[3]);
        }
    }
}

extern "C" void kernel_launch(void* const* d_in, const int* in_sizes, int n_in,
                              void* d_out, int out_size, void* d_ws, size_t ws_size,
                              hipStream_t stream) {
    const float* x    = (const float*)d_in[0];
    const float* c    = (const float*)d_in[1];
    const float* wq   = (const float*)d_in[2];
    const float* bq   = (const float*)d_in[3];
    const float* wk   = (const float*)d_in[4];
    const float* bk   = (const float*)d_in[5];
    const float* wv   = (const float*)d_in[6];
    const float* bv   = (const float*)d_in[7];
    const float* wo   = (const float*)d_in[8];
    const float* bo   = (const float*)d_in[9];
    const float* embk = (const float*)d_in[10];
    const float* embv = (const float*)d_in[11];

    unsigned short* u16 = (unsigned short*)d_ws;
    const size_t M = 1024 * 1024;
    unsigned short* wT  = u16;                 // 2M ush = 4MB
    unsigned short* qh  = u16 + 2 * M;
    unsigned short* ql  = u16 + 4 * M;
    unsigned short* kh  = u16 + 6 * M;
    unsigned short* vh  = u16 + 8 * M;         // tiled [bh][16][64][64]
    unsigned short* ath = u16 + 10 * M;        // bf16 att in [b][t][d]

    splitT_kernel<<<dim3(16, 16, 4), 256, 0, stream>>>(wq, wk, wv, wo, wT);

    proj_mfma<<<dim3(4, 64, 3), 256, 0, stream>>>(x, c, wT, bq, bk, bv,
                                                  qh, ql, kh, vh);

    attn_mfma<<<dim3(16, 8, 4), 512, 0, stream>>>(qh, ql, kh, vh,
                                                  embk, embv, ath);

    outproj_mfma<<<dim3(8, 64), 256, 0, stream>>>(ath,
                                                  wT + (size_t)3 * 2 * ND * ND,
                                                  bo, (float*)d_out);
}

// Round 10
// 149.744 us; speedup vs baseline: 1.2314x; 1.2314x over previous
//
#include <hip/hip_runtime.h>
#include <hip/hip_bf16.h>

#define NB 4
#define NT 1024
#define ND 512
#define NH 8
#define NKC 64

typedef __bf16 bf16x8 __attribute__((ext_vector_type(8)));
typedef float f32x4 __attribute__((ext_vector_type(4)));
typedef unsigned int u32;

__device__ __forceinline__ f32x4 MFMA(bf16x8 a, bf16x8 b, f32x4 c) {
    return __builtin_amdgcn_mfma_f32_16x16x32_bf16(a, b, c, 0, 0, 0);
}
__device__ __forceinline__ unsigned short f2bu(float v) {
    __hip_bfloat16 b = __float2bfloat16(v);
    return *(unsigned short*)&b;
}
__device__ __forceinline__ void split1(float v, unsigned short& h, unsigned short& l)
{
    __hip_bfloat16 hb = __float2bfloat16(v);
    float r = v - __bfloat162float(hb);
    __hip_bfloat16 lb = __float2bfloat16(r);
    h = *(unsigned short*)&hb;
    l = *(unsigned short*)&lb;
}
__device__ __forceinline__ void splitpack(const float4 a, const float4 b, uint4& h, uint4& l)
{
    union { unsigned short u[8]; uint4 v; } H, L;
    const float f[8] = {a.x, a.y, a.z, a.w, b.x, b.y, b.z, b.w};
    #pragma unroll
    for (int j = 0; j < 8; ++j) split1(f[j], H.u[j], L.u[j]);
    h = H.v; l = L.v;
}
// async global->LDS, 16B per lane. LDS dest = wave-uniform base + lane*16.
__device__ __forceinline__ void gl16(const unsigned short* g, unsigned short* l) {
    __builtin_amdgcn_global_load_lds(
        (const __attribute__((address_space(1))) u32*)g,
        (__attribute__((address_space(3))) u32*)l, 16, 0, 0);
}

// w[k][n] fp32 -> wT hi/lo bf16 [n][k]
__global__ __launch_bounds__(256)
void splitT_kernel(const float* __restrict__ w0, const float* __restrict__ w1,
                   const float* __restrict__ w2, const float* __restrict__ w3,
                   unsigned short* __restrict__ wT)
{
    __shared__ float tl[32][33];
    const float* w = (blockIdx.z == 0) ? w0 : (blockIdx.z == 1) ? w1
                   : (blockIdx.z == 2) ? w2 : w3;
    unsigned short* hi = wT + (size_t)blockIdx.z * 2 * (ND * ND);
    unsigned short* lo = hi + ND * ND;
    const int t = threadIdx.x;
    const int x0 = blockIdx.x * 32, y0 = blockIdx.y * 32;
    {
        const int r = t >> 3, c = (t & 7) * 4;
        const float4 v = *(const float4*)&w[(size_t)(y0 + r) * ND + x0 + c];
        tl[r][c] = v.x; tl[r][c+1] = v.y; tl[r][c+2] = v.z; tl[r][c+3] = v.w;
    }
    __syncthreads();
    {
        const int nr = t >> 3, k4 = (t & 7) * 4;
        unsigned short hh[4], ll[4];
        #pragma unroll
        for (int j = 0; j < 4; ++j) split1(tl[k4 + j][nr], hh[j], ll[j]);
        ushort4 h = make_ushort4(hh[0], hh[1], hh[2], hh[3]);
        ushort4 l = make_ushort4(ll[0], ll[1], ll[2], ll[3]);
        *(ushort4*)&hi[(size_t)(x0 + nr) * ND + y0 + k4] = h;
        *(ushort4*)&lo[(size_t)(x0 + nr) * ND + y0 + k4] = l;
    }
}

// ===========================================================================
// Projections: 64(m) x 128(n) tile, BK=64 (8 k-steps, 16 barriers total).
// A reg-staged (fp32->hi/lo split overlapped with MFMA), padded stride 72.
// B staged via global_load_lds DMA into LINEAR [128][64] LDS with source-XOR
// swizzle (chunk ^= row&7) + matching XOR on fragment reads.
// q -> hi/lo [bh][t][kc]; k -> bf16 [bh][t][kc]; v -> TILED.
// ===========================================================================
__global__ __launch_bounds__(256, 3)
void proj_mfma(const float* __restrict__ x, const float* __restrict__ cc,
               const unsigned short* __restrict__ wT,
               const float* __restrict__ bq, const float* __restrict__ bk,
               const float* __restrict__ bv,
               unsigned short* __restrict__ qh_o, unsigned short* __restrict__ ql_o,
               unsigned short* __restrict__ kh_o, unsigned short* __restrict__ vh_o)
{
    __shared__ unsigned short smem[25600];           // 50 KB -> 3 blocks/CU
    unsigned short* Ah = smem;                       // 64*72 = 4608 (padded)
    unsigned short* Al = smem + 4608;                // 64*72
    unsigned short* Bh = smem + 9216;                // 128*64 = 8192 (linear)
    unsigned short* Bl = smem + 17408;               // 128*64
    unsigned short* Tr = smem;                       // alias: 256*40 = 10240

    // XCD-aware remap of grid (4, 64, 3): 768 blocks, chunk 96 per XCD.
    const int hw = blockIdx.x + 4 * blockIdx.y + 256 * blockIdx.z;
    const int swz = (hw & 7) * 96 + (hw >> 3);
    const int xt = swz & 3;
    const int yt = (swz >> 2) & 63;
    const int which = swz >> 8;

    const float* A_g = (which == 0) ? x : cc;
    const unsigned short* Bh_g = wT + (size_t)which * 2 * (ND * ND);
    const unsigned short* Bl_g = Bh_g + ND * ND;
    const float* bias = (which == 0) ? bq : (which == 1) ? bk : bv;

    const int tid = threadIdx.x, l = tid & 63, w = tid >> 6;
    const int quad = l >> 4, lc = l & 15;
    const int wm = w & 1, wn = w >> 1;
    const int n0 = xt * 128, m0 = yt * 64;

    const int am = tid >> 2, ak = (tid & 3) * 16;
    const size_t aG = (size_t)(m0 + am) * ND + ak;

    // B DMA lane mapping: wave w stages rows [w*32, w*32+32), 4 issues of
    // 8 rows per buffer. lane -> (row lr 0..7, chunk lc8), src XOR-swizzled.
    const int lr = l >> 3, lc8 = l & 7;
    const int cs = lc8 ^ lr;
    const size_t bRow = (size_t)(n0 + w * 32 + lr) * ND + cs * 8;
    const unsigned short* bH0 = Bh_g + bRow;
    const unsigned short* bL0 = Bl_g + bRow;
    unsigned short* dBh = Bh + w * 2048;
    unsigned short* dBl = Bl + w * 2048;

    float4 ra0 = *(const float4*)&A_g[aG];
    float4 ra1 = *(const float4*)&A_g[aG + 4];
    float4 ra2 = *(const float4*)&A_g[aG + 8];
    float4 ra3 = *(const float4*)&A_g[aG + 12];
    uint4 h0, l0, h1, l1;
    splitpack(ra0, ra1, h0, l0);
    splitpack(ra2, ra3, h1, l1);

    // read-side swizzle for B fragments
    const int swz8 = lc & 7;

    f32x4 acc[2][4];
    #pragma unroll
    for (int mi = 0; mi < 2; ++mi)
        #pragma unroll
        for (int ni = 0; ni < 4; ++ni) acc[mi][ni] = (f32x4){0.f, 0.f, 0.f, 0.f};

    for (int k0 = 0; k0 < ND; k0 += 64) {
        __syncthreads();
        {
            *(uint4*)&Ah[am * 72 + ak]     = h0;
            *(uint4*)&Al[am * 72 + ak]     = l0;
            *(uint4*)&Ah[am * 72 + ak + 8] = h1;
            *(uint4*)&Al[am * 72 + ak + 8] = l1;
            #pragma unroll
            for (int j = 0; j < 4; ++j) {
                gl16(bH0 + j * 4096 + k0, dBh + j * 512);
                gl16(bL0 + j * 4096 + k0, dBl + j * 512);
            }
        }
        __syncthreads();
        if (k0 + 64 < ND) {
            const size_t aN = aG + k0 + 64;
            ra0 = *(const float4*)&A_g[aN];
            ra1 = *(const float4*)&A_g[aN + 4];
            ra2 = *(const float4*)&A_g[aN + 8];
            ra3 = *(const float4*)&A_g[aN + 12];
        }

        #pragma unroll
        for (int kk = 0; kk < 2; ++kk) {
            bf16x8 ah[2], al2[2], bh[4], bl[4];
            #pragma unroll
            for (int mi = 0; mi < 2; ++mi) {
                const int ar = (wm * 32 + mi * 16 + lc) * 72 + (kk * 4 + quad) * 8;
                ah[mi] = *(const bf16x8*)&Ah[ar];
                al2[mi] = *(const bf16x8*)&Al[ar];
            }
            #pragma unroll
            for (int ni = 0; ni < 4; ++ni) {
                const int br = (wn * 64 + ni * 16 + lc) * 64 + ((kk * 4 + quad) ^ swz8) * 8;
                bh[ni] = *(const bf16x8*)&Bh[br];
                bl[ni] = *(const bf16x8*)&Bl[br];
            }
            #pragma unroll
            for (int mi = 0; mi < 2; ++mi)
                #pragma unroll
                for (int ni = 0; ni < 4; ++ni) {
                    acc[mi][ni] = MFMA(al2[mi], bh[ni], acc[mi][ni]);
                    acc[mi][ni] = MFMA(ah[mi], bl[ni], acc[mi][ni]);
                    acc[mi][ni] = MFMA(ah[mi], bh[ni], acc[mi][ni]);
                }
        }
        if (k0 + 64 < ND) {                       // overlaps next MFMA wait
            splitpack(ra0, ra1, h0, l0);
            splitpack(ra2, ra3, h1, l1);
        }
    }

    // ---- epilogue ----
    const int bb = m0 >> 10, tt0 = m0 & 1023;
    const int hh = tt0 >> 7, cch0 = (tt0 & 127) >> 1;
    const int bh_idx = bb * NH + hh;

    if (which == 2) {   // v: tiled store [bh][t>>6][cch][t&63]
        #pragma unroll
        for (int ni = 0; ni < 4; ++ni) {
            const int n = n0 + wn * 64 + ni * 16 + lc;
            const float bval = bias[n];
            #pragma unroll
            for (int mi = 0; mi < 2; ++mi)
                #pragma unroll
                for (int r = 0; r < 4; ++r) {
                    const int mloc = wm * 32 + mi * 16 + quad * 4 + r;
                    const int cch = cch0 + (mloc >> 1);
                    const int t = (mloc & 1) * 512 + n;
                    vh_o[(((size_t)bh_idx * 16 + (t >> 6)) * 64 + cch) * 64 + (t & 63)] =
                        f2bu(acc[mi][ni][r] + bval);
                }
        }
        return;
    }

    const int npass = (which == 0) ? 2 : 1;
    unsigned short* outp[2] = {(which == 0) ? qh_o : kh_o, ql_o};

    for (int pass = 0; pass < npass; ++pass) {
        __syncthreads();
        #pragma unroll
        for (int ni = 0; ni < 4; ++ni) {
            const int nloc = wn * 64 + ni * 16 + lc;
            const float bval = bias[n0 + nloc];
            #pragma unroll
            for (int mi = 0; mi < 2; ++mi)
                #pragma unroll
                for (int r = 0; r < 4; ++r) {
                    const int mloc = wm * 32 + mi * 16 + quad * 4 + r;
                    const float val = acc[mi][ni][r] + bval;
                    unsigned short hs, ls;
                    if (which == 0) { split1(val, hs, ls); }
                    else { hs = f2bu(val); ls = 0; }
                    Tr[((mloc & 1) * 128 + nloc) * 40 + (mloc >> 1)] =
                        (pass == 0) ? hs : ls;
                }
        }
        __syncthreads();
        {
            const int t = (tid >> 7) * 512 + n0 + (tid & 127);
            const size_t oa = ((size_t)bh_idx * NT + t) * NKC + cch0;
            const uint4 v0 = *(const uint4*)&Tr[tid * 40];
            const uint4 v1 = *(const uint4*)&Tr[tid * 40 + 8];
            const uint4 v2 = *(const uint4*)&Tr[tid * 40 + 16];
            const uint4 v3 = *(const uint4*)&Tr[tid * 40 + 24];
            *(uint4*)&outp[pass][oa]      = v0;
            *(uint4*)&outp[pass][oa + 8]  = v1;
            *(uint4*)&outp[pass][oa + 16] = v2;
            *(uint4*)&outp[pass][oa + 24] = v3;
        }
    }
}

// ===========================================================================
// Output projection: 64x64 tile. ALL staging (A = att bf16, B = wo hi/lo)
// via global_load_lds DMA, linear LDS + source-XOR swizzle. No reg round-trip.
// ===========================================================================
__global__ __launch_bounds__(256, 4)
void outproj_mfma(const unsigned short* __restrict__ a_g,
                  const unsigned short* __restrict__ wTh,
                  const float* __restrict__ bo, float* __restrict__ out)
{
    __shared__ unsigned short smem2[6144];           // 12 KB
    unsigned short* As = smem2;                      // 64*32 linear
    unsigned short* Bh = smem2 + 2048;
    unsigned short* Bl = smem2 + 4096;
    const unsigned short* Bl_g = wTh + ND * ND;
    const int tid = threadIdx.x, l = tid & 63, w = tid >> 6;
    const int quad = l >> 4, lc = l & 15;
    const int wm = w & 1, wn = w >> 1;

    const int hw = blockIdx.x + 8 * blockIdx.y;      // grid (8, 64): 512 blocks
    const int swz = (hw & 7) * 64 + (hw >> 3);
    const int n0 = (swz & 7) * 64, m0 = (swz >> 3) * 64;

    // DMA lane mapping: each wave stages 16 rows per buffer (64 rows / 4 waves)
    const int lr = l >> 2, lc4 = l & 3;
    const int lcs = lc4 ^ ((lr >> 1) & 3);
    const unsigned short* asrc  = a_g + (size_t)(m0 + w * 16 + lr) * ND + lcs * 8;
    const unsigned short* bhsrc = wTh + (size_t)(n0 + w * 16 + lr) * ND + lcs * 8;
    const unsigned short* blsrc = Bl_g + (size_t)(n0 + w * 16 + lr) * ND + lcs * 8;
    unsigned short* adst = As + (w * 16) * 32;
    unsigned short* bhdst = Bh + (w * 16) * 32;
    unsigned short* bldst = Bl + (w * 16) * 32;

    const int fsw = (lc >> 1) & 3;
    const int chunk = (quad ^ fsw) * 8;

    f32x4 acc[2][2];
    #pragma unroll
    for (int mi = 0; mi < 2; ++mi)
        #pragma unroll
        for (int ni = 0; ni < 2; ++ni) acc[mi][ni] = (f32x4){0.f, 0.f, 0.f, 0.f};

    for (int k0 = 0; k0 < ND; k0 += 32) {
        __syncthreads();
        gl16(asrc + k0, adst);
        gl16(bhsrc + k0, bhdst);
        gl16(blsrc + k0, bldst);
        __syncthreads();

        bf16x8 ab[2], bhf[2], blf[2];
        #pragma unroll
        for (int mi = 0; mi < 2; ++mi)
            ab[mi] = *(const bf16x8*)&As[(wm * 32 + mi * 16 + lc) * 32 + chunk];
        #pragma unroll
        for (int ni = 0; ni < 2; ++ni) {
            const int br = (wn * 32 + ni * 16 + lc) * 32 + chunk;
            bhf[ni] = *(const bf16x8*)&Bh[br];
            blf[ni] = *(const bf16x8*)&Bl[br];
        }
        #pragma unroll
        for (int mi = 0; mi < 2; ++mi)
            #pragma unroll
            for (int ni = 0; ni < 2; ++ni) {
                acc[mi][ni] = MFMA(ab[mi], bhf[ni], acc[mi][ni]);
                acc[mi][ni] = MFMA(ab[mi], blf[ni], acc[mi][ni]);
            }
    }

    #pragma unroll
    for (int ni = 0; ni < 2; ++ni) {
        const int n = n0 + wn * 32 + ni * 16 + lc;
        const float bval = bo[n];
        #pragma unroll
        for (int mi = 0; mi < 2; ++mi)
            #pragma unroll
            for (int r = 0; r < 4; ++r) {
                const int m = m0 + wm * 32 + mi * 16 + quad * 4 + r;
                out[(size_t)m * ND + n] = acc[mi][ni][r] + bval;
            }
    }
}

// ===========================================================================
// MFMA flash attention (round-8 version, reverted): s-split across wave
// halves, K/V staged via global_load_lds into LINEAR 64x64 LDS per half with
// source-XOR chunk swizzle (c ^= row&7) + matching XOR on fragment reads.
// emb_v in separate padded block. Band logic gated on diag tiles.
// grid (16, 8, 4), XCD swizzle.
// ===========================================================================
__global__ __launch_bounds__(512, 4)
void attn_mfma(const unsigned short* __restrict__ qh_g, const unsigned short* __restrict__ ql_g,
               const unsigned short* __restrict__ kh_g,
               const unsigned short* __restrict__ vh_g,
               const float* __restrict__ embk, const float* __restrict__ embv,
               unsigned short* __restrict__ ath)
{
    __shared__ unsigned short smem[33792];            // 66 KB -> 2 blocks/CU
    unsigned short* Ev  = smem + 16384;
    unsigned short* Ps  = smem + 18944;
    float* bandv = (float*)(smem + 32256);
    unsigned short* EkH = smem + 18944;               // alias over Ps (preamble)
    unsigned short* EkL = EkH + 1152;

    const int tid = threadIdx.x, l = tid & 63, w = tid >> 6;
    const int quad = l >> 4, lc = l & 15;
    const int g = w & 3;                              // q-row group
    const int h = w >> 2;                             // s-half

    // XCD-aware remap of grid (16, 8, 4): 512 blocks, chunk 64 per XCD.
    const int hw = blockIdx.x + 16 * blockIdx.y + 128 * blockIdx.z;
    const int swz = (hw & 7) * 64 + (hw >> 3);
    const int q0 = (swz & 15) * 64;
    const int hh = (swz >> 4) & 7, bb = swz >> 7;

    const int sBeg = h * 512;
    const int bh = bb * NH + hh;
    const size_t qkBase = (size_t)bh * NT * NKC;
    const size_t vtBase = (size_t)bh * (16 * 64 * 64);

    unsigned short* Ksh = smem + h * 4096;            // K half base
    unsigned short* Vsh = smem + 8192 + h * 4096;     // V half base

    // DMA mapping: 256 threads per half; thread -> (row rr 0..31, chunk cc8),
    // source chunk XOR-swizzled; two issues cover rows 0..31 / 32..63.
    const int tl = tid & 255;
    const int rr = tl >> 3, cc8 = tl & 7;
    const int cs = cc8 ^ (rr & 7);
    const unsigned short* kSrc = kh_g + qkBase + (size_t)(sBeg + rr) * NKC + cs * 8;
    const unsigned short* vSrc = vh_g + vtBase + (size_t)(sBeg >> 6) * 4096 + rr * 64 + cs * 8;
    const int wvh = tl >> 6;                          // wave within half
    unsigned short* dK = Ksh + wvh * 512;
    unsigned short* dV = Vsh + wvh * 512;

    for (int idx = tid; idx < 16 * 72; idx += 512) {
        const int d = idx / 72, kc = idx - d * 72;
        const float v = (d < 9 && kc < 64) ? embk[d * 64 + kc] : 0.f;
        unsigned short hs, ls;
        split1(v, hs, ls);
        EkH[idx] = hs;
        EkL[idx] = ls;
    }
    for (int idx = tid; idx < 64 * 40; idx += 512) {
        const int c = idx / 40, d = idx - c * 40;
        Ev[idx] = f2bu((d < 9) ? embv[d * 64 + c] : 0.f);
    }
    __syncthreads();

    bf16x8 qh[2], ql[2];
    {
        const int qg = q0 + g * 16 + lc;
        const size_t qa = qkBase + (size_t)qg * NKC + quad * 8;
        qh[0] = *(const bf16x8*)&qh_g[qa];
        qh[1] = *(const bf16x8*)&qh_g[qa + 32];
        ql[0] = *(const bf16x8*)&ql_g[qa];
        ql[1] = *(const bf16x8*)&ql_g[qa + 32];
    }

    {
        f32x4 accB = (f32x4){0.f, 0.f, 0.f, 0.f};
        #pragma unroll
        for (int kk = 0; kk < 2; ++kk) {
            const bf16x8 ebh = *(const bf16x8*)&EkH[lc * 72 + kk * 32 + quad * 8];
            const bf16x8 ebl = *(const bf16x8*)&EkL[lc * 72 + kk * 32 + quad * 8];
            accB = MFMA(ql[kk], ebh, accB);
            accB = MFMA(qh[kk], ebl, accB);
            accB = MFMA(qh[kk], ebh, accB);
        }
        __syncthreads();
        if (h == 0 && lc <= 8) {
            #pragma unroll
            for (int r = 0; r < 4; ++r)
                bandv[(g * 16 + quad * 4 + r) * 12 + lc] = accB[r];
        }
    }
    unsigned short* P = Ps + w * 1664;
    {
        // zero band/pad cols 64..96 for all 16 P rows once
        const int zr = l >> 2, zc = 64 + (l & 3) * 8;
        *(uint4*)&P[zr * 104 + zc] = (uint4){0u, 0u, 0u, 0u};
    }

    // read-side swizzle for K/V fragments
    const int swz8 = lc & 7;

    f32x4 O[4];
    #pragma unroll
    for (int ci = 0; ci < 4; ++ci) O[ci] = (f32x4){0.f, 0.f, 0.f, 0.f};
    float l_run[4] = {0.f, 0.f, 0.f, 0.f};
    bool prevdiag = false;

    for (int s0 = sBeg; s0 < sBeg + 512; s0 += 64) {
        __syncthreads();
        gl16(kSrc, dK);  gl16(kSrc + 2048, dK + 2048);
        gl16(vSrc, dV);  gl16(vSrc + 2048, dV + 2048);
        kSrc += 4096; vSrc += 4096;
        __syncthreads();

        const int sd = s0 - q0;
        const bool diag = (sd >= -64) && (sd <= 64);   // wave-uniform

        // ---- QK^T: (qh+ql) x K_bf16 ----
        f32x4 S[4];
        #pragma unroll
        for (int ni = 0; ni < 4; ++ni) {
            f32x4 a = (f32x4){0.f, 0.f, 0.f, 0.f};
            #pragma unroll
            for (int kk = 0; kk < 2; ++kk) {
                const bf16x8 kb = *(const bf16x8*)
                    &Ksh[(ni * 16 + lc) * 64 + ((kk * 4 + quad) ^ swz8) * 8];
                a = MFMA(ql[kk], kb, a);
                a = MFMA(qh[kk], kb, a);
            }
            S[ni] = a;
        }

        // ---- band add (diag tiles only) ----
        if (diag) {
            #pragma unroll
            for (int ni = 0; ni < 4; ++ni)
                #pragma unroll
                for (int r = 0; r < 4; ++r) {
                    const int ql64 = g * 16 + quad * 4 + r;
                    const int dp4 = (s0 + ni * 16 + lc) - (q0 + ql64) + 4;
                    if (dp4 >= 0 && dp4 <= 8) S[ni][r] += bandv[ql64 * 12 + dp4];
                }
        }
        // ---- scale + exp (no max subtraction) ----
        #pragma unroll
        for (int ni = 0; ni < 4; ++ni)
            #pragma unroll
            for (int r = 0; r < 4; ++r)
                S[ni][r] = __expf(S[ni][r] * 0.125f);
        #pragma unroll
        for (int r = 0; r < 4; ++r)
            l_run[r] += S[0][r] + S[1][r] + S[2][r] + S[3][r];

        // ---- P -> per-wave LDS ----
        if (diag || prevdiag) {        // clear band cols only when stale
            const int zr = l >> 2, zc = 64 + (l & 3) * 4;
            *(ushort4*)&P[zr * 104 + zc] = make_ushort4(0, 0, 0, 0);
        }
        if (diag) {
            #pragma unroll
            for (int ni = 0; ni < 4; ++ni)
                #pragma unroll
                for (int r = 0; r < 4; ++r) {
                    const int prow = quad * 4 + r;
                    const unsigned short pb = f2bu(S[ni][r]);
                    P[prow * 104 + ni * 16 + lc] = pb;
                    const int dp4 = (s0 + ni * 16 + lc) - (q0 + g * 16 + prow) + 4;
                    if (dp4 >= 0 && dp4 <= 8) P[prow * 104 + 64 + dp4] = pb;
                }
        } else {
            #pragma unroll
            for (int ni = 0; ni < 4; ++ni)
                #pragma unroll
                for (int r = 0; r < 4; ++r) {
                    const int prow = quad * 4 + r;
                    P[prow * 104 + ni * 16 + lc] = f2bu(S[ni][r]);
                }
        }

        // ---- PV: ks=0,1 from V tile, ks=2 from static emb block ----
        #pragma unroll
        for (int ks = 0; ks < 2; ++ks) {
            const bf16x8 pa = *(const bf16x8*)&P[lc * 104 + ks * 32 + quad * 8];
            #pragma unroll
            for (int ci = 0; ci < 4; ++ci) {
                const bf16x8 vb = *(const bf16x8*)
                    &Vsh[(ci * 16 + lc) * 64 + ((ks * 4 + quad) ^ swz8) * 8];
                O[ci] = MFMA(pa, vb, O[ci]);
            }
        }
        {
            const bf16x8 pa = *(const bf16x8*)&P[lc * 104 + 64 + quad * 8];
            #pragma unroll
            for (int ci = 0; ci < 4; ++ci) {
                const bf16x8 vb = *(const bf16x8*)&Ev[(ci * 16 + lc) * 40 + quad * 8];
                O[ci] = MFMA(pa, vb, O[ci]);
            }
        }
        prevdiag = diag;
    }

    // ---- epilogue: reduce l over the 16 col-lanes, merge halves in LDS ----
    #pragma unroll
    for (int r = 0; r < 4; ++r) {
        float v = l_run[r];
        v += __shfl_xor(v, 1); v += __shfl_xor(v, 2);
        v += __shfl_xor(v, 4); v += __shfl_xor(v, 8);
        l_run[r] = v;
    }

    __syncthreads();                         // all waves done with K/V tiles
    float* Oex = (float*)smem;               // 64q x 64c f32 = 16 KB (over K region)
    float* l1s = bandv;                      // 64 f32 (bandv dead after loop)
    const int qloc0 = g * 16 + quad * 4;

    if (h == 1) {
        #pragma unroll
        for (int ci = 0; ci < 4; ++ci)
            #pragma unroll
            for (int r = 0; r < 4; ++r)
                Oex[(qloc0 + r) * 64 + ci * 16 + lc] = O[ci][r];
        if (lc == 0) {
            #pragma unroll
            for (int r = 0; r < 4; ++r)
                l1s[qloc0 + r] = l_run[r];
        }
    }
    __syncthreads();
    if (h == 0) {
        float linv[4];
        #pragma unroll
        for (int r = 0; r < 4; ++r)
            linv[r] = 1.f / (l_run[r] + l1s[qloc0 + r]);
        #pragma unroll
        for (int ci = 0; ci < 4; ++ci) {
            const int c = ci * 16 + lc;
            const int row = hh * 128 + 2 * c + (q0 >> 9);
            unsigned short o[4];
            #pragma unroll
            for (int r = 0; r < 4; ++r)
                o[r] = f2bu((O[ci][r] + Oex[(qloc0 + r) * 64 + c]) * linv[r]);
            *(ushort4*)&ath[((size_t)bb * NT + row) * ND + (q0 & 511) + qloc0] =
                make_ushort4(o[0], o[1], o[2], o[3]);
        }
    }
}

extern "C" void kernel_launch(void* const* d_in, const int* in_sizes, int n_in,
                              void* d_out, int out_size, void* d_ws, size_t ws_size,
                              hipStream_t stream) {
    const float* x    = (const float*)d_in[0];
    const float* c    = (const float*)d_in[1];
    const float* wq   = (const float*)d_in[2];
    const float* bq   = (const float*)d_in[3];
    const float* wk   = (const float*)d_in[4];
    const float* bk   = (const float*)d_in[5];
    const float* wv   = (const float*)d_in[6];
    const float* bv   = (const float*)d_in[7];
    const float* wo   = (const float*)d_in[8];
    const float* bo   = (const float*)d_in[9];
    const float* embk = (const float*)d_in[10];
    const float* embv = (const float*)d_in[11];

    unsigned short* u16 = (unsigned short*)d_ws;
    const size_t M = 1024 * 1024;
    unsigned short* wT  = u16;                 // 2M ush = 4MB
    unsigned short* qh  = u16 + 2 * M;
    unsigned short* ql  = u16 + 4 * M;
    unsigned short* kh  = u16 + 6 * M;
    unsigned short* vh  = u16 + 8 * M;         // tiled [bh][16][64][64]
    unsigned short* ath = u16 + 10 * M;        // bf16 att in [b][t][d]

    splitT_kernel<<<dim3(16, 16, 4), 256, 0, stream>>>(wq, wk, wv, wo, wT);

    proj_mfma<<<dim3(4, 64, 3), 256, 0, stream>>>(x, c, wT, bq, bk, bv,
                                                  qh, ql, kh, vh);

    attn_mfma<<<dim3(16, 8, 4), 512, 0, stream>>>(qh, ql, kh, vh,
                                                  embk, embv, ath);

    outproj_mfma<<<dim3(8, 64), 256, 0, stream>>>(ath,
                                                  wT + (size_t)3 * 2 * ND * ND,
                                                  bo, (float*)d_out);
}

// Round 11
// 148.652 us; speedup vs baseline: 1.2404x; 1.0073x over previous
//
#include <hip/hip_runtime.h>
#include <hip/hip_bf16.h>

#define NB 4
#define NT 1024
#define ND 512
#define NH 8
#define NKC 64

typedef __bf16 bf16x8 __attribute__((ext_vector_type(8)));
typedef float f32x4 __attribute__((ext_vector_type(4)));
typedef unsigned int u32;

__device__ __forceinline__ f32x4 MFMA(bf16x8 a, bf16x8 b, f32x4 c) {
    return __builtin_amdgcn_mfma_f32_16x16x32_bf16(a, b, c, 0, 0, 0);
}
__device__ __forceinline__ unsigned short f2bu(float v) {
    __hip_bfloat16 b = __float2bfloat16(v);
    return *(unsigned short*)&b;
}
__device__ __forceinline__ void split1(float v, unsigned short& h, unsigned short& l)
{
    __hip_bfloat16 hb = __float2bfloat16(v);
    float r = v - __bfloat162float(hb);
    __hip_bfloat16 lb = __float2bfloat16(r);
    h = *(unsigned short*)&hb;
    l = *(unsigned short*)&lb;
}
__device__ __forceinline__ void splitpack(const float4 a, const float4 b, uint4& h, uint4& l)
{
    union { unsigned short u[8]; uint4 v; } H, L;
    const float f[8] = {a.x, a.y, a.z, a.w, b.x, b.y, b.z, b.w};
    #pragma unroll
    for (int j = 0; j < 8; ++j) split1(f[j], H.u[j], L.u[j]);
    h = H.v; l = L.v;
}
// async global->LDS, 16B per lane. LDS dest = wave-uniform base + lane*16.
__device__ __forceinline__ void gl16(const unsigned short* g, unsigned short* l) {
    __builtin_amdgcn_global_load_lds(
        (const __attribute__((address_space(1))) u32*)g,
        (__attribute__((address_space(3))) u32*)l, 16, 0, 0);
}

// w[k][n] fp32 -> wT hi/lo bf16 [n][k]
__global__ __launch_bounds__(256)
void splitT_kernel(const float* __restrict__ w0, const float* __restrict__ w1,
                   const float* __restrict__ w2, const float* __restrict__ w3,
                   unsigned short* __restrict__ wT)
{
    __shared__ float tl[32][33];
    const float* w = (blockIdx.z == 0) ? w0 : (blockIdx.z == 1) ? w1
                   : (blockIdx.z == 2) ? w2 : w3;
    unsigned short* hi = wT + (size_t)blockIdx.z * 2 * (ND * ND);
    unsigned short* lo = hi + ND * ND;
    const int t = threadIdx.x;
    const int x0 = blockIdx.x * 32, y0 = blockIdx.y * 32;
    {
        const int r = t >> 3, c = (t & 7) * 4;
        const float4 v = *(const float4*)&w[(size_t)(y0 + r) * ND + x0 + c];
        tl[r][c] = v.x; tl[r][c+1] = v.y; tl[r][c+2] = v.z; tl[r][c+3] = v.w;
    }
    __syncthreads();
    {
        const int nr = t >> 3, k4 = (t & 7) * 4;
        unsigned short hh[4], ll[4];
        #pragma unroll
        for (int j = 0; j < 4; ++j) split1(tl[k4 + j][nr], hh[j], ll[j]);
        ushort4 h = make_ushort4(hh[0], hh[1], hh[2], hh[3]);
        ushort4 l = make_ushort4(ll[0], ll[1], ll[2], ll[3]);
        *(ushort4*)&hi[(size_t)(x0 + nr) * ND + y0 + k4] = h;
        *(ushort4*)&lo[(size_t)(x0 + nr) * ND + y0 + k4] = l;
    }
}

// ===========================================================================
// Projections: 64(m) x 128(n) tile, BK=32, DOUBLE-BUFFERED single-barrier
// k-loop (T3-lite): STAGE(buf^1, t+1) issued before compute(buf), one
// __syncthreads per step -> stage latency covered by compute. A reg-staged
// (split overlapped), B via global_load_lds with source-XOR swizzle.
// q -> hi/lo [bh][t][kc]; k -> bf16 [bh][t][kc]; v -> TILED.
// ===========================================================================
__global__ __launch_bounds__(256, 3)
void proj_mfma(const float* __restrict__ x, const float* __restrict__ cc,
               const unsigned short* __restrict__ wT,
               const float* __restrict__ bq, const float* __restrict__ bk,
               const float* __restrict__ bv,
               unsigned short* __restrict__ qh_o, unsigned short* __restrict__ ql_o,
               unsigned short* __restrict__ kh_o, unsigned short* __restrict__ vh_o)
{
    __shared__ unsigned short smem[26624];           // 52 KB = 2 bufs x 13312
    // buf layout: +0 Ah(64*40 pad) +2560 Al +5120 Bh(128*32 lin) +9216 Bl
    unsigned short* Tr = smem;                       // epilogue alias (256*40)

    // XCD-aware remap of grid (4, 64, 3): 768 blocks, chunk 96 per XCD.
    const int hw = blockIdx.x + 4 * blockIdx.y + 256 * blockIdx.z;
    const int swz = (hw & 7) * 96 + (hw >> 3);
    const int xt = swz & 3;
    const int yt = (swz >> 2) & 63;
    const int which = swz >> 8;

    const float* A_g = (which == 0) ? x : cc;
    const unsigned short* Bh_g = wT + (size_t)which * 2 * (ND * ND);
    const unsigned short* Bl_g = Bh_g + ND * ND;
    const float* bias = (which == 0) ? bq : (which == 1) ? bk : bv;

    const int tid = threadIdx.x, l = tid & 63, w = tid >> 6;
    const int quad = l >> 4, lc = l & 15;
    const int wm = w & 1, wn = w >> 1;
    const int n0 = xt * 128, m0 = yt * 64;

    const int am = tid >> 2, ak = (tid & 3) * 8;
    const size_t aG = (size_t)(m0 + am) * ND + ak;

    // B DMA lane mapping (r6-verified): lane -> (row lr, chunk lc4), source
    // chunk XOR-swizzled by (lr>>1)&3; LDS stays linear.
    const int lr = l >> 2, lc4 = l & 3;
    const int lcs = lc4 ^ ((lr >> 1) & 3);
    const unsigned short* bsrcH0 = Bh_g + (size_t)(n0 + w * 32 + lr) * ND + lcs * 8;
    const unsigned short* bsrcH1 = bsrcH0 + 16 * ND;
    const unsigned short* bsrcL0 = Bl_g + (size_t)(n0 + w * 32 + lr) * ND + lcs * 8;
    const unsigned short* bsrcL1 = bsrcL0 + 16 * ND;

    // read-side swizzle for B fragments
    const int fsw = (lc >> 1) & 3;
    const int bchunk = (quad ^ fsw) * 8;

    f32x4 acc[2][4];
    #pragma unroll
    for (int mi = 0; mi < 2; ++mi)
        #pragma unroll
        for (int ni = 0; ni < 4; ++ni) acc[mi][ni] = (f32x4){0.f, 0.f, 0.f, 0.f};

    auto STAGE = [&](unsigned short* base, int k0, const uint4& h, const uint4& lo4) {
        *(uint4*)&base[am * 40 + ak] = h;
        *(uint4*)&base[2560 + am * 40 + ak] = lo4;
        gl16(bsrcH0 + k0, base + 5120 + w * 1024);
        gl16(bsrcH1 + k0, base + 5120 + w * 1024 + 512);
        gl16(bsrcL0 + k0, base + 9216 + w * 1024);
        gl16(bsrcL1 + k0, base + 9216 + w * 1024 + 512);
    };
    auto COMPUTE = [&](const unsigned short* base) {
        bf16x8 ah[2], al2[2], bhf[4], blf[4];
        #pragma unroll
        for (int mi = 0; mi < 2; ++mi) {
            const int ar = (wm * 32 + mi * 16 + lc) * 40 + quad * 8;
            ah[mi]  = *(const bf16x8*)&base[ar];
            al2[mi] = *(const bf16x8*)&base[2560 + ar];
        }
        #pragma unroll
        for (int ni = 0; ni < 4; ++ni) {
            const int br = (wn * 64 + ni * 16 + lc) * 32 + bchunk;
            bhf[ni] = *(const bf16x8*)&base[5120 + br];
            blf[ni] = *(const bf16x8*)&base[9216 + br];
        }
        #pragma unroll
        for (int mi = 0; mi < 2; ++mi)
            #pragma unroll
            for (int ni = 0; ni < 4; ++ni) {
                acc[mi][ni] = MFMA(al2[mi], bhf[ni], acc[mi][ni]);
                acc[mi][ni] = MFMA(ah[mi], blf[ni], acc[mi][ni]);
                acc[mi][ni] = MFMA(ah[mi], bhf[ni], acc[mi][ni]);
            }
    };

    // ---- prologue: stage tile 0 into buf0, prefetch A regs for tile 1 ----
    float4 ra0 = *(const float4*)&A_g[aG];
    float4 ra1 = *(const float4*)&A_g[aG + 4];
    uint4 h0, l0;
    splitpack(ra0, ra1, h0, l0);
    STAGE(smem, 0, h0, l0);
    ra0 = *(const float4*)&A_g[aG + 32];
    ra1 = *(const float4*)&A_g[aG + 36];
    __syncthreads();

    #pragma unroll
    for (int k0 = 0; k0 < ND; k0 += 64) {
        // even: compute buf0 (tile k0), stage buf1 (tile k0+32)
        {
            splitpack(ra0, ra1, h0, l0);
            STAGE(smem + 13312, k0 + 32, h0, l0);
            if (k0 + 64 < ND) {
                ra0 = *(const float4*)&A_g[aG + k0 + 64];
                ra1 = *(const float4*)&A_g[aG + k0 + 68];
            }
            COMPUTE(smem);
            __syncthreads();
        }
        // odd: compute buf1 (tile k0+32), stage buf0 (tile k0+64)
        {
            if (k0 + 64 < ND) {
                splitpack(ra0, ra1, h0, l0);
                STAGE(smem, k0 + 64, h0, l0);
                if (k0 + 96 < ND) {
                    ra0 = *(const float4*)&A_g[aG + k0 + 96];
                    ra1 = *(const float4*)&A_g[aG + k0 + 100];
                }
            }
            COMPUTE(smem + 13312);
            __syncthreads();
        }
    }

    // ---- epilogue ----
    const int bb = m0 >> 10, tt0 = m0 & 1023;
    const int hh = tt0 >> 7, cch0 = (tt0 & 127) >> 1;
    const int bh_idx = bb * NH + hh;

    if (which == 2) {   // v: tiled store [bh][t>>6][cch][t&63]
        #pragma unroll
        for (int ni = 0; ni < 4; ++ni) {
            const int n = n0 + wn * 64 + ni * 16 + lc;
            const float bval = bias[n];
            #pragma unroll
            for (int mi = 0; mi < 2; ++mi)
                #pragma unroll
                for (int r = 0; r < 4; ++r) {
                    const int mloc = wm * 32 + mi * 16 + quad * 4 + r;
                    const int cch = cch0 + (mloc >> 1);
                    const int t = (mloc & 1) * 512 + n;
                    vh_o[(((size_t)bh_idx * 16 + (t >> 6)) * 64 + cch) * 64 + (t & 63)] =
                        f2bu(acc[mi][ni][r] + bval);
                }
        }
        return;
    }

    const int npass = (which == 0) ? 2 : 1;
    unsigned short* outp[2] = {(which == 0) ? qh_o : kh_o, ql_o};

    for (int pass = 0; pass < npass; ++pass) {
        __syncthreads();
        #pragma unroll
        for (int ni = 0; ni < 4; ++ni) {
            const int nloc = wn * 64 + ni * 16 + lc;
            const float bval = bias[n0 + nloc];
            #pragma unroll
            for (int mi = 0; mi < 2; ++mi)
                #pragma unroll
                for (int r = 0; r < 4; ++r) {
                    const int mloc = wm * 32 + mi * 16 + quad * 4 + r;
                    const float val = acc[mi][ni][r] + bval;
                    unsigned short hs, ls;
                    if (which == 0) { split1(val, hs, ls); }
                    else { hs = f2bu(val); ls = 0; }
                    Tr[((mloc & 1) * 128 + nloc) * 40 + (mloc >> 1)] =
                        (pass == 0) ? hs : ls;
                }
        }
        __syncthreads();
        {
            const int t = (tid >> 7) * 512 + n0 + (tid & 127);
            const size_t oa = ((size_t)bh_idx * NT + t) * NKC + cch0;
            const uint4 v0 = *(const uint4*)&Tr[tid * 40];
            const uint4 v1 = *(const uint4*)&Tr[tid * 40 + 8];
            const uint4 v2 = *(const uint4*)&Tr[tid * 40 + 16];
            const uint4 v3 = *(const uint4*)&Tr[tid * 40 + 24];
            *(uint4*)&outp[pass][oa]      = v0;
            *(uint4*)&outp[pass][oa + 8]  = v1;
            *(uint4*)&outp[pass][oa + 16] = v2;
            *(uint4*)&outp[pass][oa + 24] = v3;
        }
    }
}

// ===========================================================================
// Output projection: 64x64 tile, DOUBLE-BUFFERED single-barrier k-loop.
// ALL staging via global_load_lds DMA, linear LDS + source-XOR swizzle.
// ===========================================================================
__global__ __launch_bounds__(256, 4)
void outproj_mfma(const unsigned short* __restrict__ a_g,
                  const unsigned short* __restrict__ wTh,
                  const float* __restrict__ bo, float* __restrict__ out)
{
    __shared__ unsigned short smem2[12288];          // 24 KB = 2 bufs x 6144
    // buf layout: +0 As(64*32) +2048 Bh +4096 Bl
    const unsigned short* Bl_g = wTh + ND * ND;
    const int tid = threadIdx.x, l = tid & 63, w = tid >> 6;
    const int quad = l >> 4, lc = l & 15;
    const int wm = w & 1, wn = w >> 1;

    const int hw = blockIdx.x + 8 * blockIdx.y;      // grid (8, 64): 512 blocks
    const int swz = (hw & 7) * 64 + (hw >> 3);
    const int n0 = (swz & 7) * 64, m0 = (swz >> 3) * 64;

    // DMA lane mapping: each wave stages 16 rows per tensor
    const int lr = l >> 2, lc4 = l & 3;
    const int lcs = lc4 ^ ((lr >> 1) & 3);
    const unsigned short* asrc  = a_g + (size_t)(m0 + w * 16 + lr) * ND + lcs * 8;
    const unsigned short* bhsrc = wTh + (size_t)(n0 + w * 16 + lr) * ND + lcs * 8;
    const unsigned short* blsrc = Bl_g + (size_t)(n0 + w * 16 + lr) * ND + lcs * 8;

    const int fsw = (lc >> 1) & 3;
    const int chunk = (quad ^ fsw) * 8;

    f32x4 acc[2][2];
    #pragma unroll
    for (int mi = 0; mi < 2; ++mi)
        #pragma unroll
        for (int ni = 0; ni < 2; ++ni) acc[mi][ni] = (f32x4){0.f, 0.f, 0.f, 0.f};

    auto STAGE = [&](unsigned short* base, int k0) {
        gl16(asrc + k0, base + w * 512);
        gl16(bhsrc + k0, base + 2048 + w * 512);
        gl16(blsrc + k0, base + 4096 + w * 512);
    };
    auto COMPUTE = [&](const unsigned short* base) {
        bf16x8 ab[2], bhf[2], blf[2];
        #pragma unroll
        for (int mi = 0; mi < 2; ++mi)
            ab[mi] = *(const bf16x8*)&base[(wm * 32 + mi * 16 + lc) * 32 + chunk];
        #pragma unroll
        for (int ni = 0; ni < 2; ++ni) {
            const int br = (wn * 32 + ni * 16 + lc) * 32 + chunk;
            bhf[ni] = *(const bf16x8*)&base[2048 + br];
            blf[ni] = *(const bf16x8*)&base[4096 + br];
        }
        #pragma unroll
        for (int mi = 0; mi < 2; ++mi)
            #pragma unroll
            for (int ni = 0; ni < 2; ++ni) {
                acc[mi][ni] = MFMA(ab[mi], bhf[ni], acc[mi][ni]);
                acc[mi][ni] = MFMA(ab[mi], blf[ni], acc[mi][ni]);
            }
    };

    STAGE(smem2, 0);
    __syncthreads();
    #pragma unroll
    for (int k0 = 0; k0 < ND; k0 += 64) {
        STAGE(smem2 + 6144, k0 + 32);
        COMPUTE(smem2);
        __syncthreads();
        if (k0 + 64 < ND) STAGE(smem2, k0 + 64);
        COMPUTE(smem2 + 6144);
        __syncthreads();
    }

    #pragma unroll
    for (int ni = 0; ni < 2; ++ni) {
        const int n = n0 + wn * 32 + ni * 16 + lc;
        const float bval = bo[n];
        #pragma unroll
        for (int mi = 0; mi < 2; ++mi)
            #pragma unroll
            for (int r = 0; r < 4; ++r) {
                const int m = m0 + wm * 32 + mi * 16 + quad * 4 + r;
                out[(size_t)m * ND + n] = acc[mi][ni][r] + bval;
            }
    }
}

// ===========================================================================
// MFMA flash attention (r8 structure): s-split across wave halves, K/V via
// global_load_lds into LINEAR 64x64 LDS per half with source-XOR swizzle.
// emb_v MFMA and band-column work gated PURELY on diag tiles (exactly-zero
// contribution off-diagonal). grid (16, 8, 4), XCD swizzle.
// ===========================================================================
__global__ __launch_bounds__(512, 4)
void attn_mfma(const unsigned short* __restrict__ qh_g, const unsigned short* __restrict__ ql_g,
               const unsigned short* __restrict__ kh_g,
               const unsigned short* __restrict__ vh_g,
               const float* __restrict__ embk, const float* __restrict__ embv,
               unsigned short* __restrict__ ath)
{
    __shared__ unsigned short smem[33792];            // 66 KB -> 2 blocks/CU
    unsigned short* Ev  = smem + 16384;
    unsigned short* Ps  = smem + 18944;
    float* bandv = (float*)(smem + 32256);
    unsigned short* EkH = smem + 18944;               // alias over Ps (preamble)
    unsigned short* EkL = EkH + 1152;

    const int tid = threadIdx.x, l = tid & 63, w = tid >> 6;
    const int quad = l >> 4, lc = l & 15;
    const int g = w & 3;                              // q-row group
    const int h = w >> 2;                             // s-half

    // XCD-aware remap of grid (16, 8, 4): 512 blocks, chunk 64 per XCD.
    const int hw = blockIdx.x + 16 * blockIdx.y + 128 * blockIdx.z;
    const int swz = (hw & 7) * 64 + (hw >> 3);
    const int q0 = (swz & 15) * 64;
    const int hh = (swz >> 4) & 7, bb = swz >> 7;

    const int sBeg = h * 512;
    const int bh = bb * NH + hh;
    const size_t qkBase = (size_t)bh * NT * NKC;
    const size_t vtBase = (size_t)bh * (16 * 64 * 64);

    unsigned short* Ksh = smem + h * 4096;            // K half base
    unsigned short* Vsh = smem + 8192 + h * 4096;     // V half base

    // DMA mapping: 256 threads per half; thread -> (row rr 0..31, chunk cc8),
    // source chunk XOR-swizzled; two issues cover rows 0..31 / 32..63.
    const int tl = tid & 255;
    const int rr = tl >> 3, cc8 = tl & 7;
    const int cs = cc8 ^ (rr & 7);
    const unsigned short* kSrc = kh_g + qkBase + (size_t)(sBeg + rr) * NKC + cs * 8;
    const unsigned short* vSrc = vh_g + vtBase + (size_t)(sBeg >> 6) * 4096 + rr * 64 + cs * 8;
    const int wvh = tl >> 6;                          // wave within half
    unsigned short* dK = Ksh + wvh * 512;
    unsigned short* dV = Vsh + wvh * 512;

    for (int idx = tid; idx < 16 * 72; idx += 512) {
        const int d = idx / 72, kc = idx - d * 72;
        const float v = (d < 9 && kc < 64) ? embk[d * 64 + kc] : 0.f;
        unsigned short hs, ls;
        split1(v, hs, ls);
        EkH[idx] = hs;
        EkL[idx] = ls;
    }
    for (int idx = tid; idx < 64 * 40; idx += 512) {
        const int c = idx / 40, d = idx - c * 40;
        Ev[idx] = f2bu((d < 9) ? embv[d * 64 + c] : 0.f);
    }
    __syncthreads();

    bf16x8 qh[2], ql[2];
    {
        const int qg = q0 + g * 16 + lc;
        const size_t qa = qkBase + (size_t)qg * NKC + quad * 8;
        qh[0] = *(const bf16x8*)&qh_g[qa];
        qh[1] = *(const bf16x8*)&qh_g[qa + 32];
        ql[0] = *(const bf16x8*)&ql_g[qa];
        ql[1] = *(const bf16x8*)&ql_g[qa + 32];
    }

    {
        f32x4 accB = (f32x4){0.f, 0.f, 0.f, 0.f};
        #pragma unroll
        for (int kk = 0; kk < 2; ++kk) {
            const bf16x8 ebh = *(const bf16x8*)&EkH[lc * 72 + kk * 32 + quad * 8];
            const bf16x8 ebl = *(const bf16x8*)&EkL[lc * 72 + kk * 32 + quad * 8];
            accB = MFMA(ql[kk], ebh, accB);
            accB = MFMA(qh[kk], ebl, accB);
            accB = MFMA(qh[kk], ebh, accB);
        }
        __syncthreads();
        if (h == 0 && lc <= 8) {
            #pragma unroll
            for (int r = 0; r < 4; ++r)
                bandv[(g * 16 + quad * 4 + r) * 12 + lc] = accB[r];
        }
    }
    unsigned short* P = Ps + w * 1664;
    {
        // zero band/pad cols 64..96 for all 16 P rows once
        const int zr = l >> 2, zc = 64 + (l & 3) * 8;
        *(uint4*)&P[zr * 104 + zc] = (uint4){0u, 0u, 0u, 0u};
    }

    // read-side swizzle for K/V fragments
    const int swz8 = lc & 7;

    f32x4 O[4];
    #pragma unroll
    for (int ci = 0; ci < 4; ++ci) O[ci] = (f32x4){0.f, 0.f, 0.f, 0.f};
    float l_run[4] = {0.f, 0.f, 0.f, 0.f};

    for (int s0 = sBeg; s0 < sBeg + 512; s0 += 64) {
        __syncthreads();
        gl16(kSrc, dK);  gl16(kSrc + 2048, dK + 2048);
        gl16(vSrc, dV);  gl16(vSrc + 2048, dV + 2048);
        kSrc += 4096; vSrc += 4096;
        __syncthreads();

        const int sd = s0 - q0;
        const bool diag = (sd >= -64) && (sd <= 64);   // wave-uniform

        // ---- QK^T: (qh+ql) x K_bf16 ----
        f32x4 S[4];
        #pragma unroll
        for (int ni = 0; ni < 4; ++ni) {
            f32x4 a = (f32x4){0.f, 0.f, 0.f, 0.f};
            #pragma unroll
            for (int kk = 0; kk < 2; ++kk) {
                const bf16x8 kb = *(const bf16x8*)
                    &Ksh[(ni * 16 + lc) * 64 + ((kk * 4 + quad) ^ swz8) * 8];
                a = MFMA(ql[kk], kb, a);
                a = MFMA(qh[kk], kb, a);
            }
            S[ni] = a;
        }

        // ---- band add (diag tiles only) ----
        if (diag) {
            #pragma unroll
            for (int ni = 0; ni < 4; ++ni)
                #pragma unroll
                for (int r = 0; r < 4; ++r) {
                    const int ql64 = g * 16 + quad * 4 + r;
                    const int dp4 = (s0 + ni * 16 + lc) - (q0 + ql64) + 4;
                    if (dp4 >= 0 && dp4 <= 8) S[ni][r] += bandv[ql64 * 12 + dp4];
                }
        }
        // ---- scale + exp (no max subtraction) ----
        #pragma unroll
        for (int ni = 0; ni < 4; ++ni)
            #pragma unroll
            for (int r = 0; r < 4; ++r)
                S[ni][r] = __expf(S[ni][r] * 0.125f);
        #pragma unroll
        for (int r = 0; r < 4; ++r)
            l_run[r] += S[0][r] + S[1][r] + S[2][r] + S[3][r];

        // ---- P -> per-wave LDS ----
        if (diag) {
            {   // clear band cols for this step's partial writes
                const int zr = l >> 2, zc = 64 + (l & 3) * 4;
                *(ushort4*)&P[zr * 104 + zc] = make_ushort4(0, 0, 0, 0);
            }
            #pragma unroll
            for (int ni = 0; ni < 4; ++ni)
                #pragma unroll
                for (int r = 0; r < 4; ++r) {
                    const int prow = quad * 4 + r;
                    const unsigned short pb = f2bu(S[ni][r]);
                    P[prow * 104 + ni * 16 + lc] = pb;
                    const int dp4 = (s0 + ni * 16 + lc) - (q0 + g * 16 + prow) + 4;
                    if (dp4 >= 0 && dp4 <= 8) P[prow * 104 + 64 + dp4] = pb;
                }
        } else {
            #pragma unroll
            for (int ni = 0; ni < 4; ++ni)
                #pragma unroll
                for (int r = 0; r < 4; ++r) {
                    const int prow = quad * 4 + r;
                    P[prow * 104 + ni * 16 + lc] = f2bu(S[ni][r]);
                }
        }

        // ---- PV: ks=0,1 from V tile; emb_v MFMA only on diag tiles ----
        #pragma unroll
        for (int ks = 0; ks < 2; ++ks) {
            const bf16x8 pa = *(const bf16x8*)&P[lc * 104 + ks * 32 + quad * 8];
            #pragma unroll
            for (int ci = 0; ci < 4; ++ci) {
                const bf16x8 vb = *(const bf16x8*)
                    &Vsh[(ci * 16 + lc) * 64 + ((ks * 4 + quad) ^ swz8) * 8];
                O[ci] = MFMA(pa, vb, O[ci]);
            }
        }
        if (diag) {
            const bf16x8 pa = *(const bf16x8*)&P[lc * 104 + 64 + quad * 8];
            #pragma unroll
            for (int ci = 0; ci < 4; ++ci) {
                const bf16x8 vb = *(const bf16x8*)&Ev[(ci * 16 + lc) * 40 + quad * 8];
                O[ci] = MFMA(pa, vb, O[ci]);
            }
        }
    }

    // ---- epilogue: reduce l over the 16 col-lanes, merge halves in LDS ----
    #pragma unroll
    for (int r = 0; r < 4; ++r) {
        float v = l_run[r];
        v += __shfl_xor(v, 1); v += __shfl_xor(v, 2);
        v += __shfl_xor(v, 4); v += __shfl_xor(v, 8);
        l_run[r] = v;
    }

    __syncthreads();                         // all waves done with K/V tiles
    float* Oex = (float*)smem;               // 64q x 64c f32 = 16 KB (over K region)
    float* l1s = bandv;                      // 64 f32 (bandv dead after loop)
    const int qloc0 = g * 16 + quad * 4;

    if (h == 1) {
        #pragma unroll
        for (int ci = 0; ci < 4; ++ci)
            #pragma unroll
            for (int r = 0; r < 4; ++r)
                Oex[(qloc0 + r) * 64 + ci * 16 + lc] = O[ci][r];
        if (lc == 0) {
            #pragma unroll
            for (int r = 0; r < 4; ++r)
                l1s[qloc0 + r] = l_run[r];
        }
    }
    __syncthreads();
    if (h == 0) {
        float linv[4];
        #pragma unroll
        for (int r = 0; r < 4; ++r)
            linv[r] = 1.f / (l_run[r] + l1s[qloc0 + r]);
        #pragma unroll
        for (int ci = 0; ci < 4; ++ci) {
            const int c = ci * 16 + lc;
            const int row = hh * 128 + 2 * c + (q0 >> 9);
            unsigned short o[4];
            #pragma unroll
            for (int r = 0; r < 4; ++r)
                o[r] = f2bu((O[ci][r] + Oex[(qloc0 + r) * 64 + c]) * linv[r]);
            *(ushort4*)&ath[((size_t)bb * NT + row) * ND + (q0 & 511) + qloc0] =
                make_ushort4(o[0], o[1], o[2], o[3]);
        }
    }
}

extern "C" void kernel_launch(void* const* d_in, const int* in_sizes, int n_in,
                              void* d_out, int out_size, void* d_ws, size_t ws_size,
                              hipStream_t stream) {
    const float* x    = (const float*)d_in[0];
    const float* c    = (const float*)d_in[1];
    const float* wq   = (const float*)d_in[2];
    const float* bq   = (const float*)d_in[3];
    const float* wk   = (const float*)d_in[4];
    const float* bk   = (const float*)d_in[5];
    const float* wv   = (const float*)d_in[6];
    const float* bv   = (const float*)d_in[7];
    const float* wo   = (const float*)d_in[8];
    const float* bo   = (const float*)d_in[9];
    const float* embk = (const float*)d_in[10];
    const float* embv = (const float*)d_in[11];

    unsigned short* u16 = (unsigned short*)d_ws;
    const size_t M = 1024 * 1024;
    unsigned short* wT  = u16;                 // 2M ush = 4MB
    unsigned short* qh  = u16 + 2 * M;
    unsigned short* ql  = u16 + 4 * M;
    unsigned short* kh  = u16 + 6 * M;
    unsigned short* vh  = u16 + 8 * M;         // tiled [bh][16][64][64]
    unsigned short* ath = u16 + 10 * M;        // bf16 att in [b][t][d]

    splitT_kernel<<<dim3(16, 16, 4), 256, 0, stream>>>(wq, wk, wv, wo, wT);

    proj_mfma<<<dim3(4, 64, 3), 256, 0, stream>>>(x, c, wT, bq, bk, bv,
                                                  qh, ql, kh, vh);

    attn_mfma<<<dim3(16, 8, 4), 512, 0, stream>>>(qh, ql, kh, vh,
                                                  embk, embv, ath);

    outproj_mfma<<<dim3(8, 64), 256, 0, stream>>>(ath,
                                                  wT + (size_t)3 * 2 * ND * ND,
                                                  bo, (float*)d_out);
}